// Round 14
// baseline (162.276 us; speedup 1.0000x reference)
//
#include <hip/hip_runtime.h>
#include <hip/hip_fp16.h>

#define N_NODES 200000
#define N_EDGES 4000000
#define N_GRAPHS 512
#define D 20
#define OUT 5

#define BSH 6            // final bucket: 64 nodes
#define BN 64
#define NFB 3125         // final buckets
#define NFBP 3136        // padded = 49*64
#define NCB 49           // coarse buckets: dst>>12
#define NC 500           // chunks
#define CHUNK 8000
#define CAPA 88064       // per-coarse-region capacity (mean 81920, +21 sigma)
#define CH2 7168
#define NCH2 13          // 13*7168 >= CAPA
#define MAX_EB 1792      // max edges per final bucket (+14 sigma)
#define GMAX 8

// ---------- P0: init gsum / bucket_tot / coarse cursors ----------
__global__ void k_init(float* __restrict__ gsum, int* __restrict__ bucket_tot,
                       int* __restrict__ ccursorA) {
    int i = blockIdx.x * 256 + threadIdx.x;
    if (i < N_GRAPHS * D) gsum[i] = 0.f;
    else if (i < N_GRAPHS * D + NFBP) bucket_tot[i - N_GRAPHS * D] = 0;
    else if (i < N_GRAPHS * D + NFBP + NCB) {
        int cb = i - N_GRAPHS * D - NFBP;
        ccursorA[cb] = cb * CAPA;
    }
}

// ---------- P1: fused fine-histogram + coarse partition (one dst/src pass) ----------
__launch_bounds__(1024)
__global__ void k_histA(const int* __restrict__ src, const int* __restrict__ dst,
                        int* __restrict__ hist_g, int* __restrict__ ccursorA,
                        int* __restrict__ ebufA) {
    __shared__ int hfine[NFBP];
    __shared__ int hco[NCB];
    __shared__ int lcur[NCB];
    int t = threadIdx.x, c = blockIdx.x;
    for (int j = t; j < NFBP; j += 1024) hfine[j] = 0;
    __syncthreads();
    int base = c * CHUNK;
    for (int k = t; k < CHUNK; k += 1024) atomicAdd(&hfine[dst[base + k] >> BSH], 1);
    __syncthreads();
    if (t < NCB) {
        int s = 0;
        #pragma unroll 8
        for (int i = 0; i < 64; i++) s += hfine[(t << 6) + i];
        hco[t] = s;
        lcur[t] = atomicAdd(&ccursorA[t], s);
    }
    for (int j = t; j < NFBP; j += 1024) hist_g[c * NFBP + j] = hfine[j];
    __syncthreads();
    for (int k = t; k < CHUNK; k += 1024) {
        int d = dst[base + k];
        int sv = src[base + k];
        int cb = d >> 12;
        int pos = atomicAdd(&lcur[cb], 1);
        if (pos < (cb + 1) * CAPA) ebufA[pos] = (sv << 12) | (d & 4095);
    }
}

// ---------- P2: column sums of hist matrix -> bucket_tot ----------
__launch_bounds__(256)
__global__ void k_colsum(const int* __restrict__ hist_g, int* __restrict__ bucket_tot) {
    int col = blockIdx.x * 256 + threadIdx.x;
    if (col >= NFBP) return;
    int r0 = blockIdx.y * 50;
    int sum = 0;
    for (int r = r0; r < r0 + 50; r++) sum += hist_g[r * NFBP + col];
    if (sum) atomicAdd(&bucket_tot[col], sum);
}

// ---------- P3: exclusive scan of bucket totals; fcursor = bucket_base ----------
__launch_bounds__(1024)
__global__ void k_scan_tot(const int* __restrict__ bucket_tot, int* __restrict__ bucket_base,
                           int* __restrict__ fcursor) {
    __shared__ int ps[1024];
    int t = threadIdx.x;
    int base = t * 4;
    int loc[4];
    int sum = 0;
    #pragma unroll
    for (int j = 0; j < 4; j++) {
        int idx = base + j;
        int x = (idx < NFBP) ? bucket_tot[idx] : 0;
        loc[j] = sum;
        sum += x;
    }
    ps[t] = sum;
    __syncthreads();
    for (int off = 1; off < 1024; off <<= 1) {
        int a = (t >= off) ? ps[t - off] : 0;
        __syncthreads();
        ps[t] += a;
        __syncthreads();
    }
    int carry = (t > 0) ? ps[t - 1] : 0;
    #pragma unroll
    for (int j = 0; j < 4; j++) {
        int idx = base + j;
        if (idx < NFBP) {
            int v = carry + loc[j];
            bucket_base[idx] = v;
            fcursor[idx] = v;
        }
    }
}

// ---------- P4: fine partition within coarse regions ----------
__launch_bounds__(1024)
__global__ void k_partB(const int* __restrict__ ebufA, const int* __restrict__ ccursorA,
                        const int* __restrict__ bucket_base, int* __restrict__ fcursor,
                        int* __restrict__ ebuf) {
    int cb = blockIdx.x, j = blockIdx.y, t = threadIdx.x;
    int rbase = cb * CAPA;
    int cnt = ccursorA[cb] - rbase;
    if (cnt > CAPA) cnt = CAPA;
    int lo = rbase + j * CH2;
    int hi = lo + CH2;
    int rend = rbase + cnt;
    if (hi > rend) hi = rend;
    if (lo >= hi) return;
    __shared__ int h[64];
    __shared__ int lcur[64];
    if (t < 64) h[t] = 0;
    __syncthreads();
    for (int k = lo + t; k < hi; k += 1024) atomicAdd(&h[(ebufA[k] >> 6) & 63], 1);
    __syncthreads();
    if (t < 64) lcur[t] = atomicAdd(&fcursor[(cb << 6) + t], h[t]);
    __syncthreads();
    for (int k = lo + t; k < hi; k += 1024) {
        int p = ebufA[k];
        int sb = (p >> 6) & 63;
        int pos = atomicAdd(&lcur[sb], 1);
        ebuf[pos] = ((p >> 12) << 6) | (p & 63);       // (src<<6)|dst_local
    }
}

// ---------- P5: per-bucket degree -> offs; xh48 = f16(dinv*x), 48B rows (3 x uint4) ----------
__launch_bounds__(256)
__global__ void k_count_xh(const int* __restrict__ ebuf, const int* __restrict__ bucket_base,
                           const float4* __restrict__ x4, int* __restrict__ offs_g,
                           uint4* __restrict__ xh48) {
    __shared__ int cnt[BN];
    __shared__ int s[BN];
    __shared__ float sdi[BN];
    int b = blockIdx.x, t = threadIdx.x;
    int eb = bucket_base[b], ee = bucket_base[b + 1];
    if (t < BN) cnt[t] = 0;
    __syncthreads();
    for (int k = eb + t; k < ee; k += 256) atomicAdd(&cnt[ebuf[k] & (BN - 1)], 1);
    __syncthreads();
    int nbn = N_NODES - (b << BSH); if (nbn > BN) nbn = BN;
    int v = (t < BN) ? cnt[t] : 0;
    if (t < BN) s[t] = v;
    __syncthreads();
    for (int off = 1; off < BN; off <<= 1) {
        int a = 0;
        if (t < BN && t >= off) a = s[t - off];
        __syncthreads();
        if (t < BN) s[t] += a;
        __syncthreads();
    }
    if (t < nbn) {
        int node = (b << BSH) + t;
        offs_g[node] = eb + s[t] - v;
        sdi[t] = rsqrtf((float)(v + 1));
    }
    __syncthreads();
    int nw = nbn * 3;
    for (int j = t; j < nw; j += 256) {
        int vl = j / 3, q = j - vl * 3;
        int node = (b << BSH) + vl;
        float di = sdi[vl];
        float4 lo4 = make_float4(0.f, 0.f, 0.f, 0.f), hi4 = lo4;
        lo4 = x4[node * 5 + 2 * q];
        if (q < 2) hi4 = x4[node * 5 + 2 * q + 1];
        __half2 h0 = __float22half2_rn(make_float2(lo4.x * di, lo4.y * di));
        __half2 h1 = __float22half2_rn(make_float2(lo4.z * di, lo4.w * di));
        __half2 h2 = __float22half2_rn(make_float2(hi4.x * di, hi4.y * di));
        __half2 h3 = __float22half2_rn(make_float2(hi4.z * di, hi4.w * di));
        uint4 u;
        u.x = *(unsigned int*)&h0; u.y = *(unsigned int*)&h1;
        u.z = *(unsigned int*)&h2; u.w = *(unsigned int*)&h3;
        xh48[node * 3 + q] = u;
    }
}

// ---------- helpers ----------
__device__ __forceinline__ void acc4(float* a, unsigned lo, unsigned hi) {
    float2 f0 = __half22float2(*(__half2*)&lo);
    float2 f1 = __half22float2(*(__half2*)&hi);
    a[0] += f0.x; a[1] += f0.y; a[2] += f1.x; a[3] += f1.y;
}
__device__ __forceinline__ void acc8(float* a, uint4 m) {
    acc4(a, m.x, m.y); acc4(a + 4, m.z, m.w);
}

// ---------- P6: node-parallel gather, 3 x uint4 slices, 8x unrolled ----------
__launch_bounds__(192)
__global__ void k_gather_fused(const int* __restrict__ ebuf, const int* __restrict__ bucket_base,
                               const int* __restrict__ offs_g, const uint4* __restrict__ xh48,
                               const int* __restrict__ batch, const float* __restrict__ W1,
                               const float* __restrict__ b1, float* __restrict__ gsum) {
    __shared__ int loff[BN + 1];
    __shared__ int cur[BN];
    __shared__ int lcsr[MAX_EB];
    __shared__ float w[D * D];
    __shared__ float wb[D];
    __shared__ float sagg[BN][25];
    __shared__ float lgsum[GMAX][D];
    int b = blockIdx.x, t = threadIdx.x;
    int eb = bucket_base[b], ee = bucket_base[b + 1];
    int n = ee - eb;
    int nbn = N_NODES - (b << BSH); if (nbn > BN) nbn = BN;

    for (int j = t; j < D * D; j += 192) w[j] = W1[j];
    if (t < D) wb[t] = b1[t];
    if (t < GMAX * D) ((float*)lgsum)[t] = 0.f;
    if (t < nbn) {
        int o = offs_g[(b << BSH) + t] - eb;
        loff[t] = o;
        cur[t] = o;
    }
    if (t == 0) loff[nbn] = n;
    __syncthreads();

    for (int k = t; k < n; k += 192) {
        int p = ebuf[eb + k];
        int pos = atomicAdd(&cur[p & (BN - 1)], 1);
        if (pos < MAX_EB) lcsr[pos] = p >> BSH;
    }
    __syncthreads();

    int nw = nbn * 3;
    for (int j = t; j < nw; j += 192) {
        int vl = j / 3, q = j - vl * 3;
        int node = (b << BSH) + vl;
        float A[8] = {0.f, 0.f, 0.f, 0.f, 0.f, 0.f, 0.f, 0.f};
        float B[8] = {0.f, 0.f, 0.f, 0.f, 0.f, 0.f, 0.f, 0.f};
        acc8(A, xh48[node * 3 + q]);                    // self term (pre-scaled)
        int lo = loff[vl], hi = loff[vl + 1];
        if (hi > MAX_EB) hi = MAX_EB;
        if (lo > MAX_EB) lo = MAX_EB;
        int k = lo;
        for (; k + 8 <= hi; k += 8) {
            int s0 = lcsr[k],     s1 = lcsr[k + 1], s2 = lcsr[k + 2], s3 = lcsr[k + 3];
            int s4 = lcsr[k + 4], s5 = lcsr[k + 5], s6 = lcsr[k + 6], s7 = lcsr[k + 7];
            uint4 m0 = xh48[s0 * 3 + q];
            uint4 m1 = xh48[s1 * 3 + q];
            uint4 m2 = xh48[s2 * 3 + q];
            uint4 m3 = xh48[s3 * 3 + q];
            uint4 m4 = xh48[s4 * 3 + q];
            uint4 m5 = xh48[s5 * 3 + q];
            uint4 m6 = xh48[s6 * 3 + q];
            uint4 m7 = xh48[s7 * 3 + q];
            acc8(A, m0); acc8(B, m1); acc8(A, m2); acc8(B, m3);
            acc8(A, m4); acc8(B, m5); acc8(A, m6); acc8(B, m7);
        }
        for (; k + 4 <= hi; k += 4) {
            int s0 = lcsr[k], s1 = lcsr[k + 1], s2 = lcsr[k + 2], s3 = lcsr[k + 3];
            uint4 m0 = xh48[s0 * 3 + q];
            uint4 m1 = xh48[s1 * 3 + q];
            uint4 m2 = xh48[s2 * 3 + q];
            uint4 m3 = xh48[s3 * 3 + q];
            acc8(A, m0); acc8(B, m1); acc8(A, m2); acc8(B, m3);
        }
        for (; k < hi; k++) acc8(A, xh48[lcsr[k] * 3 + q]);
        #pragma unroll
        for (int r = 0; r < 8; r++) sagg[vl][q * 8 + r] = A[r] + B[r];
    }
    __syncthreads();

    int g0 = batch[b << BSH];
    int glast = batch[(b << BSH) + nbn - 1];
    int gcnt = glast - g0 + 1;

    if (t < nbn) {
        int node = (b << BSH) + t;
        float di = rsqrtf((float)(loff[t + 1] - loff[t] + 1));
        int gi = batch[node] - g0;
        float pre[D];
        #pragma unroll
        for (int d = 0; d < D; d++) pre[d] = sagg[t][d];
        int t20 = t % D;
        bool fits = (gcnt <= GMAX);
        for (int jj = 0; jj < D; jj++) {
            int o = t20 + jj; if (o >= D) o -= D;
            float h = 0.f;
            #pragma unroll
            for (int d = 0; d < D; d++) h = fmaf(pre[d], w[d * D + o], h);
            h = fmaf(h, di, wb[o]);
            h = fmaxf(h, 0.f);
            if (fits) atomicAdd(&lgsum[gi][o], h);
            else atomicAdd(&gsum[(g0 + gi) * D + o], h);  // safety path
        }
    }
    __syncthreads();
    if (gcnt <= GMAX && t < gcnt * D) {
        atomicAdd(&gsum[(g0 + t / D) * D + (t % D)], lgsum[t / D][t % D]);
    }
}

// ---------- P7: head: mean -> W_out -> softmax ----------
__launch_bounds__(64)
__global__ void k_head(const float* __restrict__ gsum, const int* __restrict__ batch,
                       const float* __restrict__ W_out, const float* __restrict__ b_out,
                       float* __restrict__ out) {
    __shared__ float wo[D * OUT];
    __shared__ float bo[OUT];
    int t = threadIdx.x;
    for (int j = t; j < D * OUT; j += 64) wo[j] = W_out[j];
    if (t < OUT) bo[t] = b_out[t];
    __syncthreads();
    int g = blockIdx.x * 64 + t;
    if (g >= N_GRAPHS) return;
    auto lb = [&](int key) {
        int lo = 0, hi = N_NODES;
        while (lo < hi) { int mid = (lo + hi) >> 1; if (batch[mid] < key) lo = mid + 1; else hi = mid; }
        return lo;
    };
    int cnt = lb(g + 1) - lb(g);
    float inv = 1.0f / fmaxf((float)cnt, 1.0f);
    float logits[OUT];
    #pragma unroll
    for (int o = 0; o < OUT; o++) logits[o] = bo[o];
    #pragma unroll
    for (int d = 0; d < D; d++) {
        float p = gsum[g * D + d] * inv;
        #pragma unroll
        for (int o = 0; o < OUT; o++) logits[o] = fmaf(p, wo[d * OUT + o], logits[o]);
    }
    float m = logits[0];
    #pragma unroll
    for (int o = 1; o < OUT; o++) m = fmaxf(m, logits[o]);
    float ex[OUT], sum = 0.f;
    #pragma unroll
    for (int o = 0; o < OUT; o++) { ex[o] = __expf(logits[o] - m); sum += ex[o]; }
    float isum = 1.0f / sum;
    #pragma unroll
    for (int o = 0; o < OUT; o++) out[g * OUT + o] = ex[o] * isum;
}

extern "C" void kernel_launch(void* const* d_in, const int* in_sizes, int n_in,
                              void* d_out, int out_size, void* d_ws, size_t ws_size,
                              hipStream_t stream) {
    const float* x     = (const float*)d_in[0];
    const int*   edge  = (const int*)d_in[1];
    const int*   batch = (const int*)d_in[2];
    const float* W1    = (const float*)d_in[3];
    const float* b1    = (const float*)d_in[4];
    const float* W_out = (const float*)d_in[5];
    const float* b_out = (const float*)d_in[6];
    float* out = (float*)d_out;

    const int* src = edge;
    const int* dst = edge + N_EDGES;
    char* ws = (char*)d_ws;

    // workspace layout (bytes), total 50,011,392 (< 50.4 MB proven in R3):
    int*   bucket_tot  = (int*)(ws);                  // 3136*4 = 12,544
    int*   bucket_base = (int*)(ws + 12544);          // 12,544
    int*   fcursor     = (int*)(ws + 25088);          // 12,544
    int*   ccursorA    = (int*)(ws + 37632);          // 64*4
    float* gsum        = (float*)(ws + 37888);        // 40,960
    int*   offs_g      = (int*)(ws + 78848);          // 800,000
    uint4* xh48        = (uint4*)(ws + 878848);       // 9,600,000 (48B rows, 16B-aligned)
    int*   ebufA       = (int*)(ws + 10478848);       // 49*88064*4 = 17,260,544
    int*   ebuf        = (int*)(ws + 27739392);       // 16,000,000
    int*   hist_g      = (int*)(ws + 43739392);       // 500*3136*4 = 6,272,000

    k_init<<<64, 256, 0, stream>>>(gsum, bucket_tot, ccursorA);
    k_histA<<<NC, 1024, 0, stream>>>(src, dst, hist_g, ccursorA, ebufA);
    k_colsum<<<dim3(13, 10), 256, 0, stream>>>(hist_g, bucket_tot);
    k_scan_tot<<<1, 1024, 0, stream>>>(bucket_tot, bucket_base, fcursor);
    k_partB<<<dim3(NCB, NCH2), 1024, 0, stream>>>(ebufA, ccursorA, bucket_base, fcursor, ebuf);
    k_count_xh<<<NFB, 256, 0, stream>>>(ebuf, bucket_base, (const float4*)x, offs_g, xh48);
    k_gather_fused<<<NFB, 192, 0, stream>>>(ebuf, bucket_base, offs_g, xh48, batch, W1, b1, gsum);
    k_head<<<(N_GRAPHS + 63) / 64, 64, 0, stream>>>(gsum, batch, W_out, b_out, out);
}

// Round 15
// 151.946 us; speedup vs baseline: 1.0680x; 1.0680x over previous
//
#include <hip/hip_runtime.h>
#include <hip/hip_fp16.h>

#define N_NODES 200000
#define N_EDGES 4000000
#define N_GRAPHS 512
#define D 20
#define OUT 5

#define BSH 6            // final bucket: 64 nodes
#define BN 64
#define NFB 3125         // final buckets = ceil(200000/64)
#define NFBP 3136        // padded = 49*64
#define NCB 49           // coarse buckets: dst>>12 (4096 nodes)
#define NC 500           // chunks for hist/partA
#define CHUNK 8000
#define CH2 7168         // partB chunk (within coarse segment)
#define NCH2 13          // 13*7168 = 93184 >= coarse max (+40 sigma)
#define MAX_EB 1792      // max edges per final bucket (mean 1280, +14 sigma)
#define GMAX 8

// ---------- P1: per-chunk FINAL-bucket histogram; block 0 zeros gsum & bucket_tot ----------
__launch_bounds__(1024)
__global__ void k_hist(const int* __restrict__ dst, int* __restrict__ hist_g,
                       float* __restrict__ gsum, int* __restrict__ bucket_tot) {
    __shared__ int h[NFBP];
    int t = threadIdx.x;
    if (blockIdx.x == 0) {
        for (int j = t; j < N_GRAPHS * D; j += 1024) gsum[j] = 0.f;
        for (int j = t; j < NFBP; j += 1024) bucket_tot[j] = 0;
    }
    for (int j = t; j < NFBP; j += 1024) h[j] = 0;
    __syncthreads();
    int base = blockIdx.x * CHUNK;
    for (int k = t; k < CHUNK; k += 1024) atomicAdd(&h[dst[base + k] >> BSH], 1);
    __syncthreads();
    for (int j = t; j < NFBP; j += 1024) hist_g[blockIdx.x * NFBP + j] = h[j];
}

// ---------- P2: column sums of hist matrix -> bucket_tot (row-coalesced, atomic reduce) ----------
__launch_bounds__(256)
__global__ void k_colsum(const int* __restrict__ hist_g, int* __restrict__ bucket_tot) {
    int col = blockIdx.x * 256 + threadIdx.x;          // 13 x-blocks * 256 = 3328 >= 3136
    if (col >= NFBP) return;
    int r0 = blockIdx.y * 50;                          // 10 y-blocks * 50 = 500 rows
    int sum = 0;
    for (int r = r0; r < r0 + 50; r++) sum += hist_g[r * NFBP + col];
    if (sum) atomicAdd(&bucket_tot[col], sum);
}

// ---------- P3: exclusive scan of bucket totals; init fcursor & coarse cursors ----------
__launch_bounds__(1024)
__global__ void k_scan_tot(const int* __restrict__ bucket_tot, int* __restrict__ bucket_base,
                           int* __restrict__ fcursor, int* __restrict__ ccursorA) {
    __shared__ int ps[1024];
    int t = threadIdx.x;
    int base = t * 4;                                  // 4096 >= NFBP
    int loc[4];
    int sum = 0;
    #pragma unroll
    for (int j = 0; j < 4; j++) {
        int idx = base + j;
        int x = (idx < NFBP) ? bucket_tot[idx] : 0;
        loc[j] = sum;
        sum += x;
    }
    ps[t] = sum;
    __syncthreads();
    for (int off = 1; off < 1024; off <<= 1) {
        int a = (t >= off) ? ps[t - off] : 0;
        __syncthreads();
        ps[t] += a;
        __syncthreads();
    }
    int carry = (t > 0) ? ps[t - 1] : 0;
    #pragma unroll
    for (int j = 0; j < 4; j++) {
        int idx = base + j;
        if (idx < NFBP) {
            int v = carry + loc[j];
            bucket_base[idx] = v;
            fcursor[idx] = v;
        }
    }
    __syncthreads();
    if (t < NCB) ccursorA[t] = bucket_base[t << 6];
}

// ---------- P4a: coarse partition (49 buckets), cursor-reserved ----------
__launch_bounds__(1024)
__global__ void k_partA(const int* __restrict__ src, const int* __restrict__ dst,
                        int* __restrict__ ccursorA, int* __restrict__ ebufA) {
    __shared__ int h[NCB];
    __shared__ int lcur[NCB];
    int t = threadIdx.x, c = blockIdx.x;
    if (t < NCB) h[t] = 0;
    __syncthreads();
    int base = c * CHUNK;
    for (int k = t; k < CHUNK; k += 1024) atomicAdd(&h[dst[base + k] >> 12], 1);
    __syncthreads();
    if (t < NCB) lcur[t] = atomicAdd(&ccursorA[t], h[t]);   // global reserve
    __syncthreads();
    for (int k = t; k < CHUNK; k += 1024) {
        int d = dst[base + k];
        int sv = src[base + k];
        int cb = d >> 12;
        int pos = atomicAdd(&lcur[cb], 1);
        ebufA[pos] = (sv << 12) | (d & 4095);
    }
}

// ---------- P4b: fine partition within coarse (64 sub-buckets) ----------
__launch_bounds__(1024)
__global__ void k_partB(const int* __restrict__ ebufA, const int* __restrict__ bucket_base,
                        int* __restrict__ fcursor, int* __restrict__ ebuf) {
    int cb = blockIdx.x, j = blockIdx.y, t = threadIdx.x;
    int cbase = bucket_base[cb << 6];
    int cend_idx = (cb + 1) << 6; if (cend_idx > NFB) cend_idx = NFB;
    int cend = bucket_base[cend_idx];
    int lo = cbase + j * CH2;
    int hi = lo + CH2; if (hi > cend) hi = cend;
    if (lo >= hi) return;                              // uniform exit, pre-sync
    __shared__ int h[64];
    __shared__ int lcur[64];
    if (t < 64) h[t] = 0;
    __syncthreads();
    for (int k = lo + t; k < hi; k += 1024) atomicAdd(&h[(ebufA[k] >> 6) & 63], 1);
    __syncthreads();
    if (t < 64) lcur[t] = atomicAdd(&fcursor[(cb << 6) + t], h[t]);
    __syncthreads();
    for (int k = lo + t; k < hi; k += 1024) {
        int p = ebufA[k];
        int sb = (p >> 6) & 63;
        int pos = atomicAdd(&lcur[sb], 1);
        ebuf[pos] = ((p >> 12) << 6) | (p & 63);       // (src<<6)|dst_local
    }
}

// ---------- P5: per-bucket degree -> offs; xh = f16(dinv * x), packed 40B rows ----------
__launch_bounds__(256)
__global__ void k_count_xh(const int* __restrict__ ebuf, const int* __restrict__ bucket_base,
                           const float4* __restrict__ x4, int* __restrict__ offs_g,
                           uint2* __restrict__ xh2) {
    __shared__ int cnt[BN];
    __shared__ int s[BN];
    __shared__ float sdi[BN];
    int b = blockIdx.x, t = threadIdx.x;
    int eb = bucket_base[b], ee = bucket_base[b + 1];
    if (t < BN) cnt[t] = 0;
    __syncthreads();
    for (int k = eb + t; k < ee; k += 256) atomicAdd(&cnt[ebuf[k] & (BN - 1)], 1);
    __syncthreads();
    int nbn = N_NODES - (b << BSH); if (nbn > BN) nbn = BN;
    int v = (t < BN) ? cnt[t] : 0;
    if (t < BN) s[t] = v;
    __syncthreads();
    for (int off = 1; off < BN; off <<= 1) {
        int a = 0;
        if (t < BN && t >= off) a = s[t - off];
        __syncthreads();
        if (t < BN) s[t] += a;
        __syncthreads();
    }
    if (t < nbn) {
        int node = (b << BSH) + t;
        offs_g[node] = eb + s[t] - v;
        sdi[t] = rsqrtf((float)(v + 1));
    }
    __syncthreads();
    int nw = nbn * 5;
    for (int j = t; j < nw; j += 256) {
        int vl = j / 5, q = j - vl * 5;
        int node = (b << BSH) + vl;
        float4 xv = x4[node * 5 + q];
        float di = sdi[vl];
        __half2 h0 = __float22half2_rn(make_float2(xv.x * di, xv.y * di));
        __half2 h1 = __float22half2_rn(make_float2(xv.z * di, xv.w * di));
        uint2 u;
        u.x = *(unsigned int*)&h0;
        u.y = *(unsigned int*)&h1;
        xh2[node * 5 + q] = u;
    }
}

// ---------- helper: accumulate one uint2 (4 f16) ----------
__device__ __forceinline__ void accu(float& ax, float& ay, float& az, float& aw, uint2 m) {
    float2 m0 = __half22float2(*(__half2*)&m.x);
    float2 m1 = __half22float2(*(__half2*)&m.y);
    ax += m0.x; ay += m0.y; az += m1.x; aw += m1.y;
}

// ---------- P6: node-parallel gather (16x unrolled, deep MLP) + W1 matvec + relu + pool ----------
__launch_bounds__(256, 8)
__global__ void k_gather_fused(const int* __restrict__ ebuf, const int* __restrict__ bucket_base,
                               const int* __restrict__ offs_g, const uint2* __restrict__ xh2,
                               const int* __restrict__ batch, const float* __restrict__ W1,
                               const float* __restrict__ b1, float* __restrict__ gsum) {
    __shared__ int loff[BN + 1];
    __shared__ int cur[BN];
    __shared__ int lcsr[MAX_EB];
    __shared__ float w[D * D];
    __shared__ float wb[D];
    __shared__ float sagg[BN][21];
    __shared__ float lgsum[GMAX][D];
    int b = blockIdx.x, t = threadIdx.x;
    int eb = bucket_base[b], ee = bucket_base[b + 1];
    int n = ee - eb;
    int nbn = N_NODES - (b << BSH); if (nbn > BN) nbn = BN;

    for (int j = t; j < D * D; j += 256) w[j] = W1[j];
    if (t < D) wb[t] = b1[t];
    if (t < GMAX * D) ((float*)lgsum)[t] = 0.f;
    if (t < nbn) {
        int o = offs_g[(b << BSH) + t] - eb;
        loff[t] = o;
        cur[t] = o;
    }
    if (t == 0) loff[nbn] = n;
    __syncthreads();

    for (int k = t; k < n; k += 256) {
        int p = ebuf[eb + k];
        int pos = atomicAdd(&cur[p & (BN - 1)], 1);
        if (pos < MAX_EB) lcsr[pos] = p >> BSH;
    }
    __syncthreads();

    int nw = nbn * 5;
    for (int j = t; j < nw; j += 256) {
        int vl = j / 5, q = j - vl * 5;
        int node = (b << BSH) + vl;
        float ax = 0.f, ay = 0.f, az = 0.f, aw_ = 0.f;
        float bx = 0.f, by = 0.f, bz = 0.f, bw = 0.f;
        accu(ax, ay, az, aw_, xh2[node * 5 + q]);       // self term (pre-scaled)
        int lo = loff[vl], hi = loff[vl + 1];
        if (hi > MAX_EB) hi = MAX_EB;
        if (lo > MAX_EB) lo = MAX_EB;
        int k = lo;
        for (; k + 16 <= hi; k += 16) {
            int s0 = lcsr[k],      s1 = lcsr[k + 1],  s2 = lcsr[k + 2],  s3 = lcsr[k + 3];
            int s4 = lcsr[k + 4],  s5 = lcsr[k + 5],  s6 = lcsr[k + 6],  s7 = lcsr[k + 7];
            int s8 = lcsr[k + 8],  s9 = lcsr[k + 9],  sa = lcsr[k + 10], sb = lcsr[k + 11];
            int sc = lcsr[k + 12], sd = lcsr[k + 13], se = lcsr[k + 14], sf = lcsr[k + 15];
            uint2 m0 = xh2[s0 * 5 + q];
            uint2 m1 = xh2[s1 * 5 + q];
            uint2 m2 = xh2[s2 * 5 + q];
            uint2 m3 = xh2[s3 * 5 + q];
            uint2 m4 = xh2[s4 * 5 + q];
            uint2 m5 = xh2[s5 * 5 + q];
            uint2 m6 = xh2[s6 * 5 + q];
            uint2 m7 = xh2[s7 * 5 + q];
            uint2 m8 = xh2[s8 * 5 + q];
            uint2 m9 = xh2[s9 * 5 + q];
            uint2 ma = xh2[sa * 5 + q];
            uint2 mb = xh2[sb * 5 + q];
            uint2 mc = xh2[sc * 5 + q];
            uint2 md = xh2[sd * 5 + q];
            uint2 me = xh2[se * 5 + q];
            uint2 mf = xh2[sf * 5 + q];
            accu(ax, ay, az, aw_, m0); accu(bx, by, bz, bw, m1);
            accu(ax, ay, az, aw_, m2); accu(bx, by, bz, bw, m3);
            accu(ax, ay, az, aw_, m4); accu(bx, by, bz, bw, m5);
            accu(ax, ay, az, aw_, m6); accu(bx, by, bz, bw, m7);
            accu(ax, ay, az, aw_, m8); accu(bx, by, bz, bw, m9);
            accu(ax, ay, az, aw_, ma); accu(bx, by, bz, bw, mb);
            accu(ax, ay, az, aw_, mc); accu(bx, by, bz, bw, md);
            accu(ax, ay, az, aw_, me); accu(bx, by, bz, bw, mf);
        }
        for (; k + 8 <= hi; k += 8) {
            int s0 = lcsr[k],     s1 = lcsr[k + 1], s2 = lcsr[k + 2], s3 = lcsr[k + 3];
            int s4 = lcsr[k + 4], s5 = lcsr[k + 5], s6 = lcsr[k + 6], s7 = lcsr[k + 7];
            uint2 m0 = xh2[s0 * 5 + q];
            uint2 m1 = xh2[s1 * 5 + q];
            uint2 m2 = xh2[s2 * 5 + q];
            uint2 m3 = xh2[s3 * 5 + q];
            uint2 m4 = xh2[s4 * 5 + q];
            uint2 m5 = xh2[s5 * 5 + q];
            uint2 m6 = xh2[s6 * 5 + q];
            uint2 m7 = xh2[s7 * 5 + q];
            accu(ax, ay, az, aw_, m0); accu(bx, by, bz, bw, m1);
            accu(ax, ay, az, aw_, m2); accu(bx, by, bz, bw, m3);
            accu(ax, ay, az, aw_, m4); accu(bx, by, bz, bw, m5);
            accu(ax, ay, az, aw_, m6); accu(bx, by, bz, bw, m7);
        }
        for (; k + 4 <= hi; k += 4) {
            int s0 = lcsr[k], s1 = lcsr[k + 1], s2 = lcsr[k + 2], s3 = lcsr[k + 3];
            uint2 m0 = xh2[s0 * 5 + q];
            uint2 m1 = xh2[s1 * 5 + q];
            uint2 m2 = xh2[s2 * 5 + q];
            uint2 m3 = xh2[s3 * 5 + q];
            accu(ax, ay, az, aw_, m0); accu(bx, by, bz, bw, m1);
            accu(ax, ay, az, aw_, m2); accu(bx, by, bz, bw, m3);
        }
        for (; k < hi; k++) accu(ax, ay, az, aw_, xh2[lcsr[k] * 5 + q]);
        sagg[vl][q * 4 + 0] = ax + bx;
        sagg[vl][q * 4 + 1] = ay + by;
        sagg[vl][q * 4 + 2] = az + bz;
        sagg[vl][q * 4 + 3] = aw_ + bw;
    }
    __syncthreads();

    int g0 = batch[b << BSH];
    int glast = batch[(b << BSH) + nbn - 1];
    int gcnt = glast - g0 + 1;

    if (t < nbn) {
        int node = (b << BSH) + t;
        float di = rsqrtf((float)(loff[t + 1] - loff[t] + 1));
        int gi = batch[node] - g0;
        float pre[D];
        #pragma unroll
        for (int d = 0; d < D; d++) pre[d] = sagg[t][d];
        int t20 = t % D;
        bool fits = (gcnt <= GMAX);
        for (int jj = 0; jj < D; jj++) {
            int o = t20 + jj; if (o >= D) o -= D;
            float h = 0.f;
            #pragma unroll
            for (int d = 0; d < D; d++) h = fmaf(pre[d], w[d * D + o], h);
            h = fmaf(h, di, wb[o]);
            h = fmaxf(h, 0.f);
            if (fits) atomicAdd(&lgsum[gi][o], h);
            else atomicAdd(&gsum[(g0 + gi) * D + o], h);  // safety path
        }
    }
    __syncthreads();
    if (gcnt <= GMAX && t < gcnt * D) {
        atomicAdd(&gsum[(g0 + t / D) * D + (t % D)], lgsum[t / D][t % D]);
    }
}

// ---------- P7: head: mean -> W_out -> softmax ----------
__launch_bounds__(64)
__global__ void k_head(const float* __restrict__ gsum, const int* __restrict__ batch,
                       const float* __restrict__ W_out, const float* __restrict__ b_out,
                       float* __restrict__ out) {
    __shared__ float wo[D * OUT];
    __shared__ float bo[OUT];
    int t = threadIdx.x;
    for (int j = t; j < D * OUT; j += 64) wo[j] = W_out[j];
    if (t < OUT) bo[t] = b_out[t];
    __syncthreads();
    int g = blockIdx.x * 64 + t;
    if (g >= N_GRAPHS) return;
    auto lb = [&](int key) {
        int lo = 0, hi = N_NODES;
        while (lo < hi) { int mid = (lo + hi) >> 1; if (batch[mid] < key) lo = mid + 1; else hi = mid; }
        return lo;
    };
    int cnt = lb(g + 1) - lb(g);
    float inv = 1.0f / fmaxf((float)cnt, 1.0f);
    float logits[OUT];
    #pragma unroll
    for (int o = 0; o < OUT; o++) logits[o] = bo[o];
    #pragma unroll
    for (int d = 0; d < D; d++) {
        float p = gsum[g * D + d] * inv;
        #pragma unroll
        for (int o = 0; o < OUT; o++) logits[o] = fmaf(p, wo[d * OUT + o], logits[o]);
    }
    float m = logits[0];
    #pragma unroll
    for (int o = 1; o < OUT; o++) m = fmaxf(m, logits[o]);
    float ex[OUT], sum = 0.f;
    #pragma unroll
    for (int o = 0; o < OUT; o++) { ex[o] = __expf(logits[o] - m); sum += ex[o]; }
    float isum = 1.0f / sum;
    #pragma unroll
    for (int o = 0; o < OUT; o++) out[g * OUT + o] = ex[o] * isum;
}

extern "C" void kernel_launch(void* const* d_in, const int* in_sizes, int n_in,
                              void* d_out, int out_size, void* d_ws, size_t ws_size,
                              hipStream_t stream) {
    const float* x     = (const float*)d_in[0];
    const int*   edge  = (const int*)d_in[1];
    const int*   batch = (const int*)d_in[2];
    const float* W1    = (const float*)d_in[3];
    const float* b1    = (const float*)d_in[4];
    const float* W_out = (const float*)d_in[5];
    const float* b_out = (const float*)d_in[6];
    float* out = (float*)d_out;

    const int* src = edge;
    const int* dst = edge + N_EDGES;
    char* ws = (char*)d_ws;

    // workspace layout (bytes), total ~47.2 MB (ws >= 50.4 MB proven in R3):
    int*   hist_g      = (int*)(ws);                  // 500*3136*4 = 6,272,000
    int*   bucket_tot  = (int*)(ws + 6272000);        // 3136*4
    int*   bucket_base = (int*)(ws + 6284544);        // 3136*4
    int*   fcursor     = (int*)(ws + 6297088);        // 3136*4
    int*   ccursorA    = (int*)(ws + 6309632);        // 64*4
    float* gsum        = (float*)(ws + 6309888);      // 512*20*4
    int*   offs_g      = (int*)(ws + 6350848);        // 800,000
    uint2* xh2         = (uint2*)(ws + 7150848);      // 8,000,000
    int*   ebufA       = (int*)(ws + 15150848);       // 16,000,000
    int*   ebuf        = (int*)(ws + 31150848);       // 16,000,000

    k_hist<<<NC, 1024, 0, stream>>>(dst, hist_g, gsum, bucket_tot);
    k_colsum<<<dim3(13, 10), 256, 0, stream>>>(hist_g, bucket_tot);
    k_scan_tot<<<1, 1024, 0, stream>>>(bucket_tot, bucket_base, fcursor, ccursorA);
    k_partA<<<NC, 1024, 0, stream>>>(src, dst, ccursorA, ebufA);
    k_partB<<<dim3(NCB, NCH2), 1024, 0, stream>>>(ebufA, bucket_base, fcursor, ebuf);
    k_count_xh<<<NFB, 256, 0, stream>>>(ebuf, bucket_base, (const float4*)x, offs_g, xh2);
    k_gather_fused<<<NFB, 256, 0, stream>>>(ebuf, bucket_base, offs_g, xh2, batch, W1, b1, gsum);
    k_head<<<(N_GRAPHS + 63) / 64, 64, 0, stream>>>(gsum, batch, W_out, b_out, out);
}